// Round 1
// baseline (712.167 us; speedup 1.0000x reference)
//
#include <hip/hip_runtime.h>

#define IN_F   8192
#define OUT_F  16384
#define BATCH  32
#define KBLKS  2                      // split-K across blocks
#define NWAVE  4                      // waves per block (split-K within block)
#define KSLICE (IN_F / KBLKS / NWAVE) // 1024 K per wave

typedef __attribute__((ext_vector_type(8))) short  bf16x8;
typedef __attribute__((ext_vector_type(4))) float  f32x4;

// fp32 -> bf16 bits, round-to-nearest-even
__device__ __forceinline__ unsigned f2bf(float f) {
    unsigned u = __builtin_bit_cast(unsigned, f);
    return (u + 0x7fffu + ((u >> 16) & 1u)) >> 16;
}

// Exact bf16 pack of two ints in [0,256): (float)i has zero low-16 mantissa
// bits, so bf16 = high half of the fp32 bits, no rounding.
__device__ __forceinline__ unsigned pk_i2bf(int a, int b) {
    unsigned fa = __builtin_bit_cast(unsigned, (float)a);
    unsigned fb = __builtin_bit_cast(unsigned, (float)b);
#if __has_builtin(__builtin_amdgcn_perm)
    return __builtin_amdgcn_perm(fb, fa, 0x07060302u);  // {fb.hi, fa.hi}
#else
    return (fa >> 16) | (fb & 0xffff0000u);
#endif
}

// xbf[b][k] = bf16(x[b][k] * s), sumx[b] = sum_k x[b][k];  s = lut[129]
// (lut is exactly linear: lut[c] = (c-128)*s, so idx can stay integer in bf16)
__global__ __launch_bounds__(256) void prep_kernel(
        const float* __restrict__ x, const float* __restrict__ lut,
        unsigned short* __restrict__ xbf, float* __restrict__ sumx) {
    const int b = blockIdx.x;
    const int t = threadIdx.x;
    const float s = lut[129];
    const float4* xr = (const float4*)(x + b * IN_F);
    ushort4* xo = (ushort4*)(xbf + b * IN_F);
    float acc = 0.f;
    #pragma unroll
    for (int i = 0; i < IN_F / 4 / 256; ++i) {
        float4 v = xr[t + i * 256];
        acc += v.x + v.y + v.z + v.w;
        ushort4 o;
        o.x = (unsigned short)f2bf(v.x * s);
        o.y = (unsigned short)f2bf(v.y * s);
        o.z = (unsigned short)f2bf(v.z * s);
        o.w = (unsigned short)f2bf(v.w * s);
        xo[t + i * 256] = o;
    }
    __shared__ float red[256];
    red[t] = acc;
    __syncthreads();
    for (int off = 128; off > 0; off >>= 1) {
        if (t < off) red[t] += red[t + off];
        __syncthreads();
    }
    if (t == 0) sumx[b] = red[0];
}

// out[b][o] = bias[o] + lut[0] * sumx[b]   (lut[0] = -128*s; clears 0xAA poison)
__global__ __launch_bounds__(256) void init_kernel(
        const float* __restrict__ bias, const float* __restrict__ lut,
        const float* __restrict__ sumx, float* __restrict__ out) {
    int i = blockIdx.x * 256 + threadIdx.x;   // over 131072 float4s
    int b = i >> 12;                          // OUT_F/4 = 4096 float4s per row
    float corr = lut[0] * sumx[b];
    const float4* b4 = (const float4*)bias;
    float4 v = b4[i & 4095];
    v.x += corr; v.y += corr; v.z += corr; v.w += corr;
    ((float4*)out)[i] = v;
}

// Grid = 1024 n-tiles x 2 K-halves; 4 waves/block split K further.
// Lean body (~60 VGPR) + launch_bounds(256,8) -> 8 blocks/CU = 32 waves/CU
// for max outstanding idx loads. No LDS; split-K combined via fp32 HW atomics.
// MFMA 16x16x32 bf16: A[m=lane&15][k=(lane>>4)*8+j], C/D col=lane&15,
// row=(lane>>4)*4+reg (validated rounds 1-3).
__global__ __launch_bounds__(256, 8) void gemm_kernel(
        const unsigned short* __restrict__ xbf,
        const int* __restrict__ widx,
        float* __restrict__ out) {
    const int tid   = threadIdx.x;
    const int wave  = tid >> 6;
    const int lane  = tid & 63;
    const int col16 = lane & 15;
    const int quad  = lane >> 4;
    const int ntile = blockIdx.x >> 1;          // 0..1023
    const int kblk  = blockIdx.x & 1;           // 0..1
    const int n     = ntile * 16 + col16;
    const int k0    = (kblk * NWAVE + wave) * KSLICE + quad * 8;

    const int* wp = widx + (long)n * IN_F + k0;
    const unsigned short* xp0 = xbf + col16 * IN_F + k0;   // m = col16
    const unsigned short* xp1 = xp0 + 16 * IN_F;           // m = col16+16

    f32x4 acc0 = {0.f, 0.f, 0.f, 0.f};
    f32x4 acc1 = {0.f, 0.f, 0.f, 0.f};

    #pragma unroll 2
    for (int kk = 0; kk < KSLICE; kk += 32) {
        int4   c0 = *(const int4*)(wp + kk);
        int4   c1 = *(const int4*)(wp + kk + 4);
        bf16x8 a0 = *(const bf16x8*)(xp0 + kk);
        bf16x8 a1 = *(const bf16x8*)(xp1 + kk);

        union { unsigned u[4]; bf16x8 v; } bB;
        bB.u[0] = pk_i2bf(c0.x, c0.y);
        bB.u[1] = pk_i2bf(c0.z, c0.w);
        bB.u[2] = pk_i2bf(c1.x, c1.y);
        bB.u[3] = pk_i2bf(c1.z, c1.w);
        acc0 = __builtin_amdgcn_mfma_f32_16x16x32_bf16(a0, bB.v, acc0, 0, 0, 0);
        acc1 = __builtin_amdgcn_mfma_f32_16x16x32_bf16(a1, bB.v, acc1, 0, 0, 0);
    }

    const int row = quad * 4;
    float* op = out + (long)ntile * 16 + col16;
    #pragma unroll
    for (int r = 0; r < 4; ++r) {
        unsafeAtomicAdd(op + (long)(row + r) * OUT_F,      acc0[r]);
        unsafeAtomicAdd(op + (long)(row + r + 16) * OUT_F, acc1[r]);
    }
}

extern "C" void kernel_launch(void* const* d_in, const int* in_sizes, int n_in,
                              void* d_out, int out_size, void* d_ws, size_t ws_size,
                              hipStream_t stream) {
    const float* x    = (const float*)d_in[0];
    const float* lut  = (const float*)d_in[1];
    const float* bias = (const float*)d_in[2];
    const int*   widx = (const int*)d_in[3];
    float* out = (float*)d_out;

    unsigned short* xbf = (unsigned short*)d_ws;                    // 512 KiB
    float* sumx = (float*)((char*)d_ws + BATCH * IN_F * 2);         // 128 B

    prep_kernel<<<BATCH, 256, 0, stream>>>(x, lut, xbf, sumx);
    init_kernel<<<(BATCH * OUT_F / 4) / 256, 256, 0, stream>>>(bias, lut, sumx, out);
    gemm_kernel<<<OUT_F / 16 * KBLKS, 256, 0, stream>>>(xbf, widx, out);
}

// Round 2
// 700.154 us; speedup vs baseline: 1.0172x; 1.0172x over previous
//
#include <hip/hip_runtime.h>

#define IN_F   8192
#define OUT_F  16384
#define BATCH  32
#define KT     512                  // ints of K per staged tile (per row)
#define NTILES (IN_F / KT)          // 16 tiles
#define PITCH  2064                 // 2048 B row + 16 B pad: row r starts at bank 4r%32
                                    // -> ds_read_b128 column reads are 2-way (free), not 16-way

typedef __attribute__((ext_vector_type(8))) short  bf16x8;
typedef __attribute__((ext_vector_type(4))) float  f32x4;

// fp32 -> bf16 bits, round-to-nearest-even
__device__ __forceinline__ unsigned f2bf(float f) {
    unsigned u = __builtin_bit_cast(unsigned, f);
    return (u + 0x7fffu + ((u >> 16) & 1u)) >> 16;
}

// Exact bf16 pack of two ints in [0,256): (float)i has zero low-16 mantissa
// bits, so bf16 = high half of the fp32 bits, no rounding.
__device__ __forceinline__ unsigned pk_i2bf(int a, int b) {
    unsigned fa = __builtin_bit_cast(unsigned, (float)a);
    unsigned fb = __builtin_bit_cast(unsigned, (float)b);
#if __has_builtin(__builtin_amdgcn_perm)
    return __builtin_amdgcn_perm(fb, fa, 0x07060302u);  // {fb.hi, fa.hi}
#else
    return (fa >> 16) | (fb & 0xffff0000u);
#endif
}

// async global->LDS DMA, 16 B/lane, dest = uniform base + lane*16
__device__ __forceinline__ void async_copy16(const int* g, void* l) {
    __builtin_amdgcn_global_load_lds(
        (const __attribute__((address_space(1))) unsigned*)g,
        (__attribute__((address_space(3))) unsigned*)l,
        16, 0, 0);
}

// xbf[b][k] = bf16(x[b][k] * s), sumx[b] = sum_k x[b][k];  s = lut[129]
// (lut is exactly linear: lut[c] = (c-128)*s, so idx can stay integer in bf16)
__global__ __launch_bounds__(256) void prep_kernel(
        const float* __restrict__ x, const float* __restrict__ lut,
        unsigned short* __restrict__ xbf, float* __restrict__ sumx) {
    const int b = blockIdx.x;
    const int t = threadIdx.x;
    const float s = lut[129];
    const float4* xr = (const float4*)(x + b * IN_F);
    ushort4* xo = (ushort4*)(xbf + b * IN_F);
    float acc = 0.f;
    #pragma unroll
    for (int i = 0; i < IN_F / 4 / 256; ++i) {
        float4 v = xr[t + i * 256];
        acc += v.x + v.y + v.z + v.w;
        ushort4 o;
        o.x = (unsigned short)f2bf(v.x * s);
        o.y = (unsigned short)f2bf(v.y * s);
        o.z = (unsigned short)f2bf(v.z * s);
        o.w = (unsigned short)f2bf(v.w * s);
        xo[t + i * 256] = o;
    }
    __shared__ float red[256];
    red[t] = acc;
    __syncthreads();
    for (int off = 128; off > 0; off >>= 1) {
        if (t < off) red[t] += red[t + off];
        __syncthreads();
    }
    if (t == 0) sumx[b] = red[0];
}

// One block per 16-row n-tile, full K (no split-K across blocks -> no atomics,
// no init kernel). widx staged tile-by-tile into LDS via global_load_lds DMA:
// 32 KB in flight per block at the vmcnt wait, 4 blocks/CU resident (33 KB LDS)
// -> ~128 KB/CU in flight >> 9.2 KB Little's-law requirement for 6.3 TB/s.
// MFMA 16x16x32 bf16: A[m=lane&15][k=(lane>>4)*8+j], C/D col=lane&15,
// row=(lane>>4)*4+reg (validated in earlier rounds).
__global__ __launch_bounds__(256, 4) void gemm_kernel(
        const unsigned short* __restrict__ xbf,
        const int* __restrict__ widx,
        const float* __restrict__ bias,
        const float* __restrict__ lut,
        const float* __restrict__ sumx,
        float* __restrict__ out) {
    __shared__ char ltile[16 * PITCH];          // 33,024 B
    const int tid   = threadIdx.x;
    const int wave  = tid >> 6;
    const int lane  = tid & 63;
    const int col16 = lane & 15;
    const int quad  = lane >> 4;
    const int n0    = blockIdx.x * 16;

    const unsigned short* xp0 = xbf + col16 * IN_F + quad * 8;  // m = col16
    const unsigned short* xp1 = xp0 + 16 * IN_F;                // m = col16+16

    f32x4 acc0 = {0.f, 0.f, 0.f, 0.f};
    f32x4 acc1 = {0.f, 0.f, 0.f, 0.f};

    for (int t = 0; t < NTILES; ++t) {
        const long kt = (long)t * KT;
        // stage: wave w DMAs rows w*4..w*4+3 (2 KB each = 2 instrs of 1 KB)
        #pragma unroll
        for (int j = 0; j < 8; ++j) {
            const int r = wave * 4 + (j >> 1);
            const int h = j & 1;
            async_copy16(widx + (long)(n0 + r) * IN_F + kt + h * 256 + lane * 4,
                         ltile + r * PITCH + h * 1024);
        }
        asm volatile("s_waitcnt vmcnt(0)" ::: "memory");  // own DMAs landed
        __syncthreads();                                  // everyone's landed
        // compute: wave w consumes k sub-range [w*128, w*128+128) of the tile
        #pragma unroll
        for (int s = 0; s < 4; ++s) {
            const char* bb = ltile + col16 * PITCH + wave * 512 + s * 128 + quad * 32;
            int4 c0 = *(const int4*)(bb);
            int4 c1 = *(const int4*)(bb + 16);
            const long ka = kt + wave * 128 + s * 32;
            bf16x8 a0 = *(const bf16x8*)(xp0 + ka);
            bf16x8 a1 = *(const bf16x8*)(xp1 + ka);
            union { unsigned u[4]; bf16x8 v; } bB;
            bB.u[0] = pk_i2bf(c0.x, c0.y);
            bB.u[1] = pk_i2bf(c0.z, c0.w);
            bB.u[2] = pk_i2bf(c1.x, c1.y);
            bB.u[3] = pk_i2bf(c1.z, c1.w);
            acc0 = __builtin_amdgcn_mfma_f32_16x16x32_bf16(a0, bB.v, acc0, 0, 0, 0);
            acc1 = __builtin_amdgcn_mfma_f32_16x16x32_bf16(a1, bB.v, acc1, 0, 0, 0);
        }
        __syncthreads();   // all waves done reading before next tile overwrites
    }

    // epilogue: cross-wave (split-k within block) reduce via LDS, fuse
    // bias + lut[0]*sumx correction, direct store (out fully overwritten).
    float* red = (float*)ltile;                 // 4 x 512 floats = 8 KB
    #pragma unroll
    for (int r = 0; r < 4; ++r) {
        red[wave * 512 + (quad * 4 + r)      * 16 + col16] = acc0[r];
        red[wave * 512 + (quad * 4 + r + 16) * 16 + col16] = acc1[r];
    }
    __syncthreads();
    const float l0 = lut[0];                    // = -128*s
    #pragma unroll
    for (int e0 = 0; e0 < 2; ++e0) {
        const int e = tid + e0 * 256;           // 512 elems = 32 m x 16 n
        float v = red[e] + red[e + 512] + red[e + 1024] + red[e + 1536];
        const int m  = e >> 4;
        const int nn = e & 15;
        v += bias[n0 + nn] + l0 * sumx[m];
        out[(long)m * OUT_F + n0 + nn] = v;
    }
}

extern "C" void kernel_launch(void* const* d_in, const int* in_sizes, int n_in,
                              void* d_out, int out_size, void* d_ws, size_t ws_size,
                              hipStream_t stream) {
    const float* x    = (const float*)d_in[0];
    const float* lut  = (const float*)d_in[1];
    const float* bias = (const float*)d_in[2];
    const int*   widx = (const int*)d_in[3];
    float* out = (float*)d_out;

    unsigned short* xbf = (unsigned short*)d_ws;                    // 512 KiB
    float* sumx = (float*)((char*)d_ws + BATCH * IN_F * 2);         // 128 B

    prep_kernel<<<BATCH, 256, 0, stream>>>(x, lut, xbf, sumx);
    gemm_kernel<<<OUT_F / 16, 256, 0, stream>>>(xbf, widx, bias, lut, sumx, out);
}